// Round 18
// baseline (332.362 us; speedup 1.0000x reference)
//
#include <hip/hip_runtime.h>
#include <cstddef>

#define NN 100000
#define NE 800000
#define NG 64
#define DD 128
#define NV 8
#define NS 8           // column slices (16 bf16 = 32B each)
#define SCAN_CH 1024
#define SCAN_NB ((NN + SCAN_CH - 1) / SCAN_CH)  // 98
#define NPC 256        // dst nodes per gather chunk
#define NCHUNK ((NN + NPC - 1) / NPC)           // 391

#define CVT_BLKS 6250   // NN*8*2/256 (lane-pair cvt threads)
#define WT_BLKS 192     // 3*16384/256
#define HIST_BLKS 3125  // NE/256
#define HCH 392         // edge chunks per dst-range (fill only)
#define ECH ((NE + HCH - 1) / HCH)  // 2041 edges per chunk
#define RNG 12500       // NN/8 dst nodes per range

typedef __attribute__((ext_vector_type(8))) short bf16x8;
typedef __attribute__((ext_vector_type(4))) float f32x4;
typedef __attribute__((ext_vector_type(2))) unsigned int u32x2;

// ---------------- bf16 helpers ----------------
__device__ inline float lo2f(unsigned int u) {
  union { unsigned int i; float f; } x;
  x.i = u << 16;
  return x.f;
}
__device__ inline float hi2f(unsigned int u) {
  union { unsigned int i; float f; } x;
  x.i = u & 0xffff0000u;
  return x.f;
}
// packed f32x2 -> bf16x2 via HW instruction (RNE, 1 instr)
__device__ inline unsigned int pk2(float a, float b) {
  unsigned int r;
  asm("v_cvt_pk_bf16_f32 %0, %1, %2" : "=v"(r) : "v"(a), "v"(b));
  return r;
}
__device__ inline unsigned short f2b(float f) {
  union { float f; unsigned int i; } x;
  x.f = f;
  unsigned int r = x.i + 0x7fffu + ((x.i >> 16) & 1u);
  return (unsigned short)(r >> 16);
}

// ---------------- prep: cvt_feat (full-line both sides) + cvt_wt3 + hist ----------------
__global__ __launch_bounds__(256) void prep(const float* __restrict__ feat,
                                            const float* __restrict__ W1,
                                            const float* __restrict__ W2,
                                            const float* __restrict__ W3,
                                            const int* __restrict__ dst,
                                            unsigned short* __restrict__ xs,
                                            unsigned short* __restrict__ Wt,
                                            int* __restrict__ deg) {
  int b = blockIdx.x;
  if (b < CVT_BLKS) {
    // lane pair (node, half): pair reads a full 64B feat line; wave writes
    // 1KB fully contiguous in the sliced layout (no partial-line RMW).
    int tid = b * 256 + threadIdx.x;  // 0 .. 1.6M
    int l = tid & 63, w = tid >> 6;
    int s = w & 7, nb = w >> 3;          // slice, node-block of 32
    int node = nb * 32 + (l >> 1);
    int half = l & 1;
    const float* p = feat + (size_t)node * DD + s * 16 + half * 8;
    float4 v0 = *(const float4*)p;
    float4 v1 = *(const float4*)(p + 4);
    uint4 o;
    o.x = pk2(v0.x, v0.y);
    o.y = pk2(v0.z, v0.w);
    o.z = pk2(v1.x, v1.y);
    o.w = pk2(v1.z, v1.w);
    *(uint4*)((char*)xs + ((size_t)s * NN + node) * 32 + half * 16) = o;
  } else if (b < CVT_BLKS + WT_BLKS) {
    // W[k][n] f32 -> Wt[n][k] bf16, all three
    int idx = (b - CVT_BLKS) * 256 + threadIdx.x;
    int w = idx >> 14, r = idx & 16383;
    const float* W = (w == 0) ? W1 : (w == 1) ? W2 : W3;
    Wt[idx] = f2b(W[(r & 127) * DD + (r >> 7)]);
  } else {
    // single-pass histogram (atomics coalesce in L2; cheap)
    int e = (b - CVT_BLKS - WT_BLKS) * 256 + threadIdx.x;
    if (e < NE) atomicAdd(&deg[dst[e]], 1);
  }
}

// ---------------- CSR scans ----------------
__global__ __launch_bounds__(256) void scan1(const int* __restrict__ deg,
                                             int* __restrict__ excl,
                                             int* __restrict__ bsum) {
  __shared__ int ts[256];
  int base = blockIdx.x * SCAN_CH;
  int t = threadIdx.x;
  int v[4];
  int s = 0;
#pragma unroll
  for (int i = 0; i < 4; i++) {
    int idx = base + t * 4 + i;
    v[i] = (idx < NN) ? deg[idx] : 0;
    s += v[i];
  }
  ts[t] = s;
  __syncthreads();
  for (int off = 1; off < 256; off <<= 1) {
    int val = (t >= off) ? ts[t - off] : 0;
    __syncthreads();
    ts[t] += val;
    __syncthreads();
  }
  if (t == 255) bsum[blockIdx.x] = ts[255];
  int run = ts[t] - s;
#pragma unroll
  for (int i = 0; i < 4; i++) {
    int idx = base + t * 4 + i;
    if (idx < NN) excl[idx] = run;
    run += v[i];
  }
}

__global__ __launch_bounds__(128) void scan2(int* __restrict__ bsum, int nb) {
  __shared__ int sh[128];
  int t = threadIdx.x;
  int v = (t < nb) ? bsum[t] : 0;
  sh[t] = v;
  __syncthreads();
  for (int off = 1; off < 128; off <<= 1) {
    int u = (t >= off) ? sh[t - off] : 0;
    __syncthreads();
    sh[t] += u;
    __syncthreads();
  }
  if (t < nb) bsum[t] = sh[t] - v;  // exclusive
}

__global__ __launch_bounds__(256) void scan3(int* __restrict__ rowp,
                                             const int* __restrict__ bsum,
                                             int* __restrict__ cursor) {
  int i = blockIdx.x * blockDim.x + threadIdx.x;
  if (i < NN) {
    int v = rowp[i] + bsum[i / SCAN_CH];
    rowp[i] = v;
    cursor[i] = v;
  }
  if (i == 0) rowp[NN] = NE;
}

// ---------------- dst-ranged CSR fill (keeps csr stores XCD-local) ----------------
__global__ __launch_bounds__(256) void fill_csr(const int* __restrict__ src,
                                                const int* __restrict__ dst,
                                                int* __restrict__ cursor,
                                                int* __restrict__ csrb) {
  int r = blockIdx.x & 7, chunk = blockIdx.x >> 3;
  int lo = r * RNG, hi = lo + RNG;
  int e0 = chunk * ECH;
  int e1 = e0 + ECH;
  if (e1 > NE) e1 = NE;
  for (int e = e0 + threadIdx.x; e < e1; e += 256) {
    int d = dst[e];
    if (d >= lo && d < hi) {
      int pos = atomicAdd(&cursor[d], 1);
      csrb[pos] = src[e] << 5;
    }
  }
}

// ---------------- sliced gather -> sliced agg (32B slices, L1-bypass rows) ----------------
// slice = blockIdx.x & 7 pins each 3.2MB slice to one XCD's L2.
// Neighbor-row loads are volatile -> sc0 (L1 bypass): the slice never fits L1,
// so every row load is an L1 miss paying MSHR occupancy; sc0 reads L2 direct.
// csrb/rowp/self loads stay cached (L1 helps those streams).
__global__ __launch_bounds__(256) void gather_slice(const unsigned short* __restrict__ xs,
                                                    const int* __restrict__ csrb,
                                                    const int* __restrict__ rowp,
                                                    unsigned short* __restrict__ aggs) {
  const int s = blockIdx.x & 7;
  const int chunk = blockIdx.x >> 3;
  const char* __restrict__ xsl = (const char*)xs + (size_t)s * NN * 32;
  char* __restrict__ asl = (char*)aggs + (size_t)s * NN * 32;
  const int li = threadIdx.x & 3;
  const int grp = threadIdx.x >> 2;  // 0..63
  const int node0 = chunk * NPC;
  int node1 = node0 + NPC;
  if (node1 > NN) node1 = NN;
  const int lo8 = li * 8;
  for (int n = node0 + grp; n < node1; n += 64) {
    int beg = rowp[n], end = rowp[n + 1];
    u32x2 sv = *(const u32x2*)(xsl + (size_t)n * 32 + lo8);
    float a0 = lo2f(sv.x), a1 = hi2f(sv.x), a2 = lo2f(sv.y), a3 = hi2f(sv.y);
    float c0 = 0.f, c1 = 0.f, c2 = 0.f, c3 = 0.f;  // second bank
    int e = beg;
    int off = (beg < end) ? csrb[(beg + li < end) ? beg + li : end - 1] : 0;
    for (; e + 4 <= end; e += 4) {
      int ne = e + 4;
      int off_next = 0;
      if (ne < end) off_next = csrb[(ne + li < end) ? ne + li : end - 1];
      int o0 = __shfl(off, 0, 4);
      int o1 = __shfl(off, 1, 4);
      int o2 = __shfl(off, 2, 4);
      int o3 = __shfl(off, 3, 4);
      u32x2 v0 = *(volatile const u32x2*)(xsl + (unsigned int)o0 + lo8);
      u32x2 v1 = *(volatile const u32x2*)(xsl + (unsigned int)o1 + lo8);
      u32x2 v2 = *(volatile const u32x2*)(xsl + (unsigned int)o2 + lo8);
      u32x2 v3 = *(volatile const u32x2*)(xsl + (unsigned int)o3 + lo8);
      a0 += lo2f(v0.x); a1 += hi2f(v0.x); a2 += lo2f(v0.y); a3 += hi2f(v0.y);
      c0 += lo2f(v1.x); c1 += hi2f(v1.x); c2 += lo2f(v1.y); c3 += hi2f(v1.y);
      a0 += lo2f(v2.x); a1 += hi2f(v2.x); a2 += lo2f(v2.y); a3 += hi2f(v2.y);
      c0 += lo2f(v3.x); c1 += hi2f(v3.x); c2 += lo2f(v3.y); c3 += hi2f(v3.y);
      off = off_next;
    }
    if (e < end) {
      int rem = end - e;
      for (int j = 0; j < rem; j++) {
        int oj = __shfl(off, j, 4);
        u32x2 v = *(volatile const u32x2*)(xsl + (unsigned int)oj + lo8);
        a0 += lo2f(v.x); a1 += hi2f(v.x); a2 += lo2f(v.y); a3 += hi2f(v.y);
      }
    }
    u32x2 o;
    o.x = pk2(a0 + c0, a1 + c1);
    o.y = pk2(a2 + c2, a3 + c3);
    *(u32x2*)(asl + (size_t)n * 32 + lo8) = o;
  }
}

// ---------------- H = relu(A @ W + b) via MFMA ----------------
// A sliced bf16; H written sliced (POOL=0) or pooled (POOL=1, no H write)
template <int POOL>
__global__ __launch_bounds__(256) void gemm_mfma(const unsigned short* __restrict__ A,
                                                 const unsigned short* __restrict__ Wt,
                                                 const float* __restrict__ bias,
                                                 unsigned short* __restrict__ H,
                                                 const int* __restrict__ gid,
                                                 float* __restrict__ sums,
                                                 float* __restrict__ cnts) {
  __shared__ uint4 a_sh4[1024];  // 16KB: A tile [64][256B] swizzled
  __shared__ uint4 w_sh4[2048];  // 32KB: Wt [128][256B] swizzled; reused as f32 out
  __shared__ int gsh[64];
  char* a_sh = (char*)a_sh4;
  char* w_sh = (char*)w_sh4;
  const int t = threadIdx.x;
  const int block_row = blockIdx.x * 64;

  if (POOL) {
    if (t < 64) gsh[t] = (block_row + t < NN) ? gid[block_row + t] : -1;
  }

  // stage Wt (8 passes of 4KB)
#pragma unroll
  for (int p = 0; p < 8; p++) {
    int lin = p * 4096 + t * 16;
    int row = lin >> 8, inner = lin & 255;
    uint4 v = *(const uint4*)((const char*)Wt + lin);
    *(uint4*)(w_sh + row * 256 + (inner ^ ((row & 7) << 4))) = v;
  }
  // stage A tile from sliced layout (4 passes of 4KB)
#pragma unroll
  for (int p = 0; p < 4; p++) {
    int lin = p * 4096 + t * 16;
    int row = lin >> 8, inner = lin & 255;
    int grow = block_row + row;
    uint4 v = make_uint4(0u, 0u, 0u, 0u);
    if (grow < NN) {
      int slice = inner >> 5, half = (inner >> 4) & 1;
      v = *(const uint4*)((const char*)A + ((size_t)slice * NN + grow) * 32 + half * 16);
    }
    *(uint4*)(a_sh + row * 256 + (inner ^ ((row & 7) << 4))) = v;
  }
  __syncthreads();

  const int wid = t >> 6, lane = t & 63;
  const int rowbase = wid * 16;
  const int lr = lane & 15, lk = lane >> 4;

  f32x4 acc[8];
#pragma unroll
  for (int i = 0; i < 8; i++) acc[i] = (f32x4){0.f, 0.f, 0.f, 0.f};

#pragma unroll
  for (int c = 0; c < 4; c++) {
    int arow = rowbase + lr;
    bf16x8 af = *(const bf16x8*)(a_sh + arow * 256 + ((c * 64 + lk * 16) ^ ((arow & 7) << 4)));
#pragma unroll
    for (int nt = 0; nt < 8; nt++) {
      int bcol = nt * 16 + lr;
      bf16x8 bf = *(const bf16x8*)(w_sh + bcol * 256 + ((c * 64 + lk * 16) ^ ((bcol & 7) << 4)));
      acc[nt] = __builtin_amdgcn_mfma_f32_16x16x32_bf16(af, bf, acc[nt], 0, 0, 0);
    }
  }
  __syncthreads();  // all waves done reading w_sh

  // bias + relu, stage f32 output in w_sh as [64][128]
  float* osh = (float*)w_sh;
#pragma unroll
  for (int nt = 0; nt < 8; nt++) {
    int col = nt * 16 + lr;
    float bv = bias[col];
#pragma unroll
    for (int r = 0; r < 4; r++) {
      int row = rowbase + lk * 4 + r;
      osh[row * 128 + col] = fmaxf(acc[nt][r] + bv, 0.f);
    }
  }
  __syncthreads();

  if (POOL == 0) {
    // convert to bf16 (cvt_pk), store in sliced layout
#pragma unroll
    for (int i = 0; i < 8; i++) {
      int fidx = i * 1024 + t * 4;
      float4 v = *(const float4*)(osh + fidx);
      int row = fidx >> 7, col = fidx & 127;
      int grow = block_row + row;
      if (grow < NN) {
        int slice = col >> 4, w = col & 15;
        u32x2 o;
        o.x = pk2(v.x, v.y);
        o.y = pk2(v.z, v.w);
        *(u32x2*)(H + ((size_t)slice * NN + grow) * 16 + w) = o;
      }
    }
  } else {
    // fused per-graph pooling from f32 LDS (gid sorted)
    if (t < 128) {
      int f = t;
      float acc2 = 0.f;
      int cnt = 0;
      int cur = gsh[0];
      for (int r = 0; r < 64; r++) {
        int g = gsh[r];
        if (g < 0) break;
        if (g != cur) {
          unsafeAtomicAdd(&sums[cur * DD + f], acc2);
          if (f == 0) unsafeAtomicAdd(&cnts[cur], (float)cnt);
          acc2 = 0.f;
          cnt = 0;
          cur = g;
        }
        acc2 += osh[r * 128 + f];
        cnt++;
      }
      if (cur >= 0 && cnt > 0) {
        unsafeAtomicAdd(&sums[cur * DD + f], acc2);
        if (f == 0) unsafeAtomicAdd(&cnts[cur], (float)cnt);
      }
    }
  }
}

// ---------------- head ----------------
__global__ __launch_bounds__(512) void head(const float* __restrict__ sums,
                                            const float* __restrict__ cnts,
                                            const float* __restrict__ Wp,
                                            const float* __restrict__ bp,
                                            float* __restrict__ out) {
  int t = threadIdx.x;
  int g = t >> 3;
  int v = t & 7;
  float cnt = cnts[g];
  if (cnt < 1.f) cnt = 1.f;
  float acc = 0.f;
  for (int d = 0; d < DD; d++) acc += sums[g * DD + d] * Wp[d * NV + v];
  out[t] = acc / cnt + bp[v];
}

// ---------------- launch ----------------
extern "C" void kernel_launch(void* const* d_in, const int* in_sizes, int n_in,
                              void* d_out, int out_size, void* d_ws, size_t ws_size,
                              hipStream_t stream) {
  const float* feat = (const float*)d_in[0];
  const int* src = (const int*)d_in[1];
  const int* dst = (const int*)d_in[2];
  const int* gid = (const int*)d_in[3];
  const float* W1 = (const float*)d_in[4];
  const float* b1 = (const float*)d_in[5];
  const float* W2 = (const float*)d_in[6];
  const float* b2 = (const float*)d_in[7];
  const float* W3 = (const float*)d_in[8];
  const float* b3 = (const float*)d_in[9];
  const float* Wp = (const float*)d_in[10];
  const float* bp = (const float*)d_in[11];
  float* out = (float*)d_out;

  char* ws = (char*)d_ws;
  const size_t matb = (size_t)NN * DD;  // bf16 elements per matrix
  unsigned short* xs0 = (unsigned short*)ws;  // sliced
  unsigned short* hs = xs0 + matb;            // sliced
  unsigned short* aggs = hs + matb;           // sliced
  unsigned short* wtb = aggs + matb;          // 3 * 16384
  float* sums = (float*)(wtb + 3 * DD * DD);
  float* cnts = sums + NG * DD;
  int* deg = (int*)(cnts + NG);               // contiguous with sums/cnts for zeroing
  int* rowp = deg + NN;                       // NN+1 entries
  int* cursor = rowp + NN + 1;
  int* bsum = cursor + NN;
  int* csrb = bsum + 128;                     // byte offsets (src*32)

  const int nzero = NG * DD + NG + NN;  // sums + cnts + deg (4B words)
  hipMemsetAsync(sums, 0, (size_t)nzero * 4, stream);

  prep<<<CVT_BLKS + WT_BLKS + HIST_BLKS, 256, 0, stream>>>(feat, W1, W2, W3, dst, xs0, wtb, deg);

  scan1<<<SCAN_NB, 256, 0, stream>>>(deg, rowp, bsum);
  scan2<<<1, 128, 0, stream>>>(bsum, SCAN_NB);
  scan3<<<(NN + 255) / 256, 256, 0, stream>>>(rowp, bsum, cursor);
  fill_csr<<<8 * HCH, 256, 0, stream>>>(src, dst, cursor, csrb);

  const int ggrid = NCHUNK * NS;  // 3128
  const int mgrid = (NN + 63) / 64;
  // L1: xs0 -> aggs -> hs
  gather_slice<<<ggrid, 256, 0, stream>>>(xs0, csrb, rowp, aggs);
  gemm_mfma<0><<<mgrid, 256, 0, stream>>>(aggs, wtb, b1, hs, nullptr, nullptr, nullptr);
  // L2: hs -> aggs -> xs0
  gather_slice<<<ggrid, 256, 0, stream>>>(hs, csrb, rowp, aggs);
  gemm_mfma<0><<<mgrid, 256, 0, stream>>>(aggs, wtb + DD * DD, b2, xs0, nullptr, nullptr, nullptr);
  // L3: xs0 -> aggs -> pooled
  gather_slice<<<ggrid, 256, 0, stream>>>(xs0, csrb, rowp, aggs);
  gemm_mfma<1><<<mgrid, 256, 0, stream>>>(aggs, wtb + 2 * DD * DD, b3, nullptr, gid, sums, cnts);

  head<<<1, 512, 0, stream>>>(sums, cnts, Wp, bp, out);
}

// Round 19
// 304.607 us; speedup vs baseline: 1.0911x; 1.0911x over previous
//
#include <hip/hip_runtime.h>
#include <cstddef>

#define NN 100000
#define NE 800000
#define NG 64
#define DD 128
#define NV 8
#define SCAN_CH 1024
#define SCAN_NB ((NN + SCAN_CH - 1) / SCAN_CH)  // 98
#define NPC 256        // dst nodes per gather chunk
#define NCHUNK ((NN + NPC - 1) / NPC)           // 391

#define CVT_BLKS 6250   // NN*16/256
#define WT_BLKS 192     // 3*16384/256
#define HIST_BLKS 3125  // NE/256
#define HCH 392         // edge chunks per dst-range (fill only)
#define ECH ((NE + HCH - 1) / HCH)  // 2041 edges per chunk
#define RNG 12500       // NN/8 dst nodes per range

typedef __attribute__((ext_vector_type(8))) short bf16x8;
typedef __attribute__((ext_vector_type(4))) float f32x4;
typedef __attribute__((ext_vector_type(2))) unsigned int u32x2;

// ---------------- bf16 helpers ----------------
__device__ inline float lo2f(unsigned int u) {
  union { unsigned int i; float f; } x;
  x.i = u << 16;
  return x.f;
}
__device__ inline float hi2f(unsigned int u) {
  union { unsigned int i; float f; } x;
  x.i = u & 0xffff0000u;
  return x.f;
}
// packed f32x2 -> bf16x2 via HW instruction (RNE, 1 instr)
__device__ inline unsigned int pk2(float a, float b) {
  unsigned int r;
  asm("v_cvt_pk_bf16_f32 %0, %1, %2" : "=v"(r) : "v"(a), "v"(b));
  return r;
}
__device__ inline unsigned short f2b(float f) {
  union { float f; unsigned int i; } x;
  x.f = f;
  unsigned int r = x.i + 0x7fffu + ((x.i >> 16) & 1u);
  return (unsigned short)(r >> 16);
}

// ---------------- prep: cvt_feat (4x64B sliced) + cvt_wt3 ----------------
// xs layout: xs[s2][n][32 bf16] (64B per node per slice), s2 in 0..3
__global__ __launch_bounds__(256) void prep(const float* __restrict__ feat,
                                            const float* __restrict__ W1,
                                            const float* __restrict__ W2,
                                            const float* __restrict__ W3,
                                            unsigned short* __restrict__ xs,
                                            unsigned short* __restrict__ Wt) {
  int b = blockIdx.x;
  if (b < CVT_BLKS) {
    int tid = b * 256 + threadIdx.x;  // 0 .. 1.6M
    int n = tid >> 4, part = tid & 15;
    const float* p = feat + (size_t)n * DD + part * 8;
    float4 v0 = *(const float4*)p;
    float4 v1 = *(const float4*)(p + 4);
    uint4 o;
    o.x = pk2(v0.x, v0.y);
    o.y = pk2(v0.z, v0.w);
    o.z = pk2(v1.x, v1.y);
    o.w = pk2(v1.z, v1.w);
    int s2 = part >> 2, sub = part & 3;
    *(uint4*)((char*)xs + ((size_t)s2 * NN + n) * 64 + sub * 16) = o;
  } else {
    // W[k][n] f32 -> Wt[n][k] bf16, all three
    int idx = (b - CVT_BLKS) * 256 + threadIdx.x;
    int w = idx >> 14, r = idx & 16383;
    const float* W = (w == 0) ? W1 : (w == 1) ? W2 : W3;
    Wt[idx] = f2b(W[(r & 127) * DD + (r >> 7)]);
  }
}

// ---------------- plain full-grid histogram ----------------
__global__ __launch_bounds__(256) void hist_dst(const int* __restrict__ dst,
                                                int* __restrict__ deg) {
  int e = blockIdx.x * 256 + threadIdx.x;
  if (e < NE) atomicAdd(&deg[dst[e]], 1);
}

// ---------------- CSR scans ----------------
__global__ __launch_bounds__(256) void scan1(const int* __restrict__ deg,
                                             int* __restrict__ excl,
                                             int* __restrict__ bsum) {
  __shared__ int ts[256];
  int base = blockIdx.x * SCAN_CH;
  int t = threadIdx.x;
  int v[4];
  int s = 0;
#pragma unroll
  for (int i = 0; i < 4; i++) {
    int idx = base + t * 4 + i;
    v[i] = (idx < NN) ? deg[idx] : 0;
    s += v[i];
  }
  ts[t] = s;
  __syncthreads();
  for (int off = 1; off < 256; off <<= 1) {
    int val = (t >= off) ? ts[t - off] : 0;
    __syncthreads();
    ts[t] += val;
    __syncthreads();
  }
  if (t == 255) bsum[blockIdx.x] = ts[255];
  int run = ts[t] - s;
#pragma unroll
  for (int i = 0; i < 4; i++) {
    int idx = base + t * 4 + i;
    if (idx < NN) excl[idx] = run;
    run += v[i];
  }
}

__global__ __launch_bounds__(128) void scan2(int* __restrict__ bsum, int nb) {
  __shared__ int sh[128];
  int t = threadIdx.x;
  int v = (t < nb) ? bsum[t] : 0;
  sh[t] = v;
  __syncthreads();
  for (int off = 1; off < 128; off <<= 1) {
    int u = (t >= off) ? sh[t - off] : 0;
    __syncthreads();
    sh[t] += u;
    __syncthreads();
  }
  if (t < nb) bsum[t] = sh[t] - v;  // exclusive
}

__global__ __launch_bounds__(256) void scan3(int* __restrict__ rowp,
                                             const int* __restrict__ bsum,
                                             int* __restrict__ cursor) {
  int i = blockIdx.x * blockDim.x + threadIdx.x;
  if (i < NN) {
    int v = rowp[i] + bsum[i / SCAN_CH];
    rowp[i] = v;
    cursor[i] = v;
  }
  if (i == 0) rowp[NN] = NE;
}

// ---------------- dst-ranged CSR fill (csrb stores src*64 byte offsets) ----------------
__global__ __launch_bounds__(256) void fill_csr(const int* __restrict__ src,
                                                const int* __restrict__ dst,
                                                int* __restrict__ cursor,
                                                int* __restrict__ csrb) {
  int r = blockIdx.x & 7, chunk = blockIdx.x >> 3;
  int lo = r * RNG, hi = lo + RNG;
  int e0 = chunk * ECH;
  int e1 = e0 + ECH;
  if (e1 > NE) e1 = NE;
  for (int e = e0 + threadIdx.x; e < e1; e += 256) {
    int d = dst[e];
    if (d >= lo && d < hi) {
      int pos = atomicAdd(&cursor[d], 1);
      csrb[pos] = src[e] << 6;
    }
  }
}

// ---------------- 64B-sliced gather -> sliced agg ----------------
// 4 slices of 64B; slice s2 = blockIdx&3, blockIdx>>2&1 = chunk half
// (2 XCDs share a slice; 6.4MB slice partially L2-resident, L3 backstop).
// 8-lane groups, 8B per lane -> ONE 64B request per edge.
__global__ __launch_bounds__(256) void gather_slice(const unsigned short* __restrict__ xs,
                                                    const int* __restrict__ csrb,
                                                    const int* __restrict__ rowp,
                                                    unsigned short* __restrict__ aggs) {
  const int q = blockIdx.x & 7;
  const int s2 = q & 3, half = q >> 2;
  const int chunk = blockIdx.x >> 3;
  const char* __restrict__ xsl = (const char*)xs + (size_t)s2 * NN * 64;
  char* __restrict__ asl = (char*)aggs + (size_t)s2 * NN * 64;
  const int li = threadIdx.x & 7;
  const int grp = threadIdx.x >> 3;  // 0..31
  int node0 = chunk * NPC + half * (NPC / 2);
  int node1 = node0 + NPC / 2;
  if (node1 > NN) node1 = NN;
  const int lo8 = li * 8;
  for (int n = node0 + grp; n < node1; n += 32) {
    int beg = rowp[n], end = rowp[n + 1];
    u32x2 sv = *(const u32x2*)(xsl + (size_t)n * 64 + lo8);
    float a0 = lo2f(sv.x), a1 = hi2f(sv.x), a2 = lo2f(sv.y), a3 = hi2f(sv.y);
    float c0 = 0.f, c1 = 0.f, c2 = 0.f, c3 = 0.f;  // second bank
    int e = beg;
    int off = (beg < end) ? csrb[(beg + li < end) ? beg + li : end - 1] : 0;
    for (; e + 8 <= end; e += 8) {
      int ne = e + 8;
      int off_next = 0;
      if (ne < end) off_next = csrb[(ne + li < end) ? ne + li : end - 1];
      int o0 = __shfl(off, 0, 8);
      int o1 = __shfl(off, 1, 8);
      int o2 = __shfl(off, 2, 8);
      int o3 = __shfl(off, 3, 8);
      int o4 = __shfl(off, 4, 8);
      int o5 = __shfl(off, 5, 8);
      int o6 = __shfl(off, 6, 8);
      int o7 = __shfl(off, 7, 8);
      u32x2 v0 = *(const u32x2*)(xsl + (unsigned int)o0 + lo8);
      u32x2 v1 = *(const u32x2*)(xsl + (unsigned int)o1 + lo8);
      u32x2 v2 = *(const u32x2*)(xsl + (unsigned int)o2 + lo8);
      u32x2 v3 = *(const u32x2*)(xsl + (unsigned int)o3 + lo8);
      u32x2 v4 = *(const u32x2*)(xsl + (unsigned int)o4 + lo8);
      u32x2 v5 = *(const u32x2*)(xsl + (unsigned int)o5 + lo8);
      u32x2 v6 = *(const u32x2*)(xsl + (unsigned int)o6 + lo8);
      u32x2 v7 = *(const u32x2*)(xsl + (unsigned int)o7 + lo8);
      a0 += lo2f(v0.x); a1 += hi2f(v0.x); a2 += lo2f(v0.y); a3 += hi2f(v0.y);
      c0 += lo2f(v1.x); c1 += hi2f(v1.x); c2 += lo2f(v1.y); c3 += hi2f(v1.y);
      a0 += lo2f(v2.x); a1 += hi2f(v2.x); a2 += lo2f(v2.y); a3 += hi2f(v2.y);
      c0 += lo2f(v3.x); c1 += hi2f(v3.x); c2 += lo2f(v3.y); c3 += hi2f(v3.y);
      a0 += lo2f(v4.x); a1 += hi2f(v4.x); a2 += lo2f(v4.y); a3 += hi2f(v4.y);
      c0 += lo2f(v5.x); c1 += hi2f(v5.x); c2 += lo2f(v5.y); c3 += hi2f(v5.y);
      a0 += lo2f(v6.x); a1 += hi2f(v6.x); a2 += lo2f(v6.y); a3 += hi2f(v6.y);
      c0 += lo2f(v7.x); c1 += hi2f(v7.x); c2 += lo2f(v7.y); c3 += hi2f(v7.y);
      off = off_next;
    }
    if (e < end) {
      int rem = end - e;
      for (int j = 0; j < rem; j++) {
        int oj = __shfl(off, j, 8);
        u32x2 v = *(const u32x2*)(xsl + (unsigned int)oj + lo8);
        a0 += lo2f(v.x); a1 += hi2f(v.x); a2 += lo2f(v.y); a3 += hi2f(v.y);
      }
    }
    u32x2 o;
    o.x = pk2(a0 + c0, a1 + c1);
    o.y = pk2(a2 + c2, a3 + c3);
    *(u32x2*)(asl + (size_t)n * 64 + lo8) = o;
  }
}

// ---------------- H = relu(A @ W + b) via MFMA ----------------
// A in 4x64B sliced layout; H written sliced (POOL=0) or pooled (POOL=1)
template <int POOL>
__global__ __launch_bounds__(256) void gemm_mfma(const unsigned short* __restrict__ A,
                                                 const unsigned short* __restrict__ Wt,
                                                 const float* __restrict__ bias,
                                                 unsigned short* __restrict__ H,
                                                 const int* __restrict__ gid,
                                                 float* __restrict__ sums,
                                                 float* __restrict__ cnts) {
  __shared__ uint4 a_sh4[1024];  // 16KB: A tile [64][256B] swizzled
  __shared__ uint4 w_sh4[2048];  // 32KB: Wt [128][256B] swizzled; reused as f32 out
  __shared__ int gsh[64];
  char* a_sh = (char*)a_sh4;
  char* w_sh = (char*)w_sh4;
  const int t = threadIdx.x;
  const int block_row = blockIdx.x * 64;

  if (POOL) {
    if (t < 64) gsh[t] = (block_row + t < NN) ? gid[block_row + t] : -1;
  }

  // stage Wt (8 passes of 4KB)
#pragma unroll
  for (int p = 0; p < 8; p++) {
    int lin = p * 4096 + t * 16;
    int row = lin >> 8, inner = lin & 255;
    uint4 v = *(const uint4*)((const char*)Wt + lin);
    *(uint4*)(w_sh + row * 256 + (inner ^ ((row & 7) << 4))) = v;
  }
  // stage A tile from 4x64B sliced layout (4 passes of 4KB)
#pragma unroll
  for (int p = 0; p < 4; p++) {
    int lin = p * 4096 + t * 16;
    int row = lin >> 8, inner = lin & 255;
    int grow = block_row + row;
    uint4 v = make_uint4(0u, 0u, 0u, 0u);
    if (grow < NN) {
      int s2 = inner >> 6, sub = inner & 63;
      v = *(const uint4*)((const char*)A + ((size_t)s2 * NN + grow) * 64 + sub);
    }
    *(uint4*)(a_sh + row * 256 + (inner ^ ((row & 7) << 4))) = v;
  }
  __syncthreads();

  const int wid = t >> 6, lane = t & 63;
  const int rowbase = wid * 16;
  const int lr = lane & 15, lk = lane >> 4;

  f32x4 acc[8];
#pragma unroll
  for (int i = 0; i < 8; i++) acc[i] = (f32x4){0.f, 0.f, 0.f, 0.f};

#pragma unroll
  for (int c = 0; c < 4; c++) {
    int arow = rowbase + lr;
    bf16x8 af = *(const bf16x8*)(a_sh + arow * 256 + ((c * 64 + lk * 16) ^ ((arow & 7) << 4)));
#pragma unroll
    for (int nt = 0; nt < 8; nt++) {
      int bcol = nt * 16 + lr;
      bf16x8 bf = *(const bf16x8*)(w_sh + bcol * 256 + ((c * 64 + lk * 16) ^ ((bcol & 7) << 4)));
      acc[nt] = __builtin_amdgcn_mfma_f32_16x16x32_bf16(af, bf, acc[nt], 0, 0, 0);
    }
  }
  __syncthreads();  // all waves done reading w_sh

  // bias + relu, stage f32 output in w_sh as [64][128]
  float* osh = (float*)w_sh;
#pragma unroll
  for (int nt = 0; nt < 8; nt++) {
    int col = nt * 16 + lr;
    float bv = bias[col];
#pragma unroll
    for (int r = 0; r < 4; r++) {
      int row = rowbase + lk * 4 + r;
      osh[row * 128 + col] = fmaxf(acc[nt][r] + bv, 0.f);
    }
  }
  __syncthreads();

  if (POOL == 0) {
    // convert to bf16 (cvt_pk), store in 4x64B sliced layout
#pragma unroll
    for (int i = 0; i < 8; i++) {
      int fidx = i * 1024 + t * 4;
      float4 v = *(const float4*)(osh + fidx);
      int row = fidx >> 7, col = fidx & 127;
      int grow = block_row + row;
      if (grow < NN) {
        int s2 = col >> 5, w = col & 31;
        u32x2 o;
        o.x = pk2(v.x, v.y);
        o.y = pk2(v.z, v.w);
        *(u32x2*)(H + ((size_t)s2 * NN + grow) * 32 + w) = o;
      }
    }
  } else {
    // fused per-graph pooling from f32 LDS (gid sorted)
    if (t < 128) {
      int f = t;
      float acc2 = 0.f;
      int cnt = 0;
      int cur = gsh[0];
      for (int r = 0; r < 64; r++) {
        int g = gsh[r];
        if (g < 0) break;
        if (g != cur) {
          unsafeAtomicAdd(&sums[cur * DD + f], acc2);
          if (f == 0) unsafeAtomicAdd(&cnts[cur], (float)cnt);
          acc2 = 0.f;
          cnt = 0;
          cur = g;
        }
        acc2 += osh[r * 128 + f];
        cnt++;
      }
      if (cur >= 0 && cnt > 0) {
        unsafeAtomicAdd(&sums[cur * DD + f], acc2);
        if (f == 0) unsafeAtomicAdd(&cnts[cur], (float)cnt);
      }
    }
  }
}

// ---------------- head ----------------
__global__ __launch_bounds__(512) void head(const float* __restrict__ sums,
                                            const float* __restrict__ cnts,
                                            const float* __restrict__ Wp,
                                            const float* __restrict__ bp,
                                            float* __restrict__ out) {
  int t = threadIdx.x;
  int g = t >> 3;
  int v = t & 7;
  float cnt = cnts[g];
  if (cnt < 1.f) cnt = 1.f;
  float acc = 0.f;
  for (int d = 0; d < DD; d++) acc += sums[g * DD + d] * Wp[d * NV + v];
  out[t] = acc / cnt + bp[v];
}

// ---------------- launch ----------------
extern "C" void kernel_launch(void* const* d_in, const int* in_sizes, int n_in,
                              void* d_out, int out_size, void* d_ws, size_t ws_size,
                              hipStream_t stream) {
  const float* feat = (const float*)d_in[0];
  const int* src = (const int*)d_in[1];
  const int* dst = (const int*)d_in[2];
  const int* gid = (const int*)d_in[3];
  const float* W1 = (const float*)d_in[4];
  const float* b1 = (const float*)d_in[5];
  const float* W2 = (const float*)d_in[6];
  const float* b2 = (const float*)d_in[7];
  const float* W3 = (const float*)d_in[8];
  const float* b3 = (const float*)d_in[9];
  const float* Wp = (const float*)d_in[10];
  const float* bp = (const float*)d_in[11];
  float* out = (float*)d_out;

  char* ws = (char*)d_ws;
  const size_t matb = (size_t)NN * DD;  // bf16 elements per matrix
  unsigned short* xs0 = (unsigned short*)ws;  // sliced
  unsigned short* hs = xs0 + matb;            // sliced
  unsigned short* aggs = hs + matb;           // sliced
  unsigned short* wtb = aggs + matb;          // 3 * 16384
  float* sums = (float*)(wtb + 3 * DD * DD);
  float* cnts = sums + NG * DD;
  int* deg = (int*)(cnts + NG);               // contiguous with sums/cnts for zeroing
  int* rowp = deg + NN;                       // NN+1 entries
  int* cursor = rowp + NN + 1;
  int* bsum = cursor + NN;
  int* csrb = bsum + 128;                     // byte offsets (src*64)

  const int nzero = NG * DD + NG + NN;  // sums + cnts + deg (4B words)
  hipMemsetAsync(sums, 0, (size_t)nzero * 4, stream);

  prep<<<CVT_BLKS + WT_BLKS, 256, 0, stream>>>(feat, W1, W2, W3, xs0, wtb);
  hist_dst<<<HIST_BLKS, 256, 0, stream>>>(dst, deg);

  scan1<<<SCAN_NB, 256, 0, stream>>>(deg, rowp, bsum);
  scan2<<<1, 128, 0, stream>>>(bsum, SCAN_NB);
  scan3<<<(NN + 255) / 256, 256, 0, stream>>>(rowp, bsum, cursor);
  fill_csr<<<8 * HCH, 256, 0, stream>>>(src, dst, cursor, csrb);

  const int ggrid = NCHUNK * 8;  // 3128 (4 slices x 2 chunk-halves)
  const int mgrid = (NN + 63) / 64;
  // L1: xs0 -> aggs -> hs
  gather_slice<<<ggrid, 256, 0, stream>>>(xs0, csrb, rowp, aggs);
  gemm_mfma<0><<<mgrid, 256, 0, stream>>>(aggs, wtb, b1, hs, nullptr, nullptr, nullptr);
  // L2: hs -> aggs -> xs0
  gather_slice<<<ggrid, 256, 0, stream>>>(hs, csrb, rowp, aggs);
  gemm_mfma<0><<<mgrid, 256, 0, stream>>>(aggs, wtb + DD * DD, b2, xs0, nullptr, nullptr, nullptr);
  // L3: xs0 -> aggs -> pooled
  gather_slice<<<ggrid, 256, 0, stream>>>(xs0, csrb, rowp, aggs);
  gemm_mfma<1><<<mgrid, 256, 0, stream>>>(aggs, wtb + 2 * DD * DD, b3, nullptr, gid, sums, cnts);

  head<<<1, 512, 0, stream>>>(sums, cnts, Wp, bp, out);
}